// Round 21
// baseline (179.129 us; speedup 1.0000x reference)
//
#include <hip/hip_runtime.h>

// ---------------------------------------------------------------------------
// Fused QKV-projection + attention (B=8, C=2048, N=512), fp32 in/out.
// Round 21: FOLD-SCALED PV. R20's pv (67us, 513 TF) was stalled by its
// reg-staged A path (global P load -> fp16 scale -> ds_write -> barrier, L3
// latency > compute window each step). sc[row][t] is constant per 128-col
// k-tile, so pv now runs the PROVEN gemm_core shape with A AND B both via
// global_load_lds (unscaled P'), accumulating each k-tile into tmp and
// folding acc += sc*tmp in fp32 at tile boundaries (32 FMA/lane x 16 — noise).
// fp32 fold is numerically better than the old fp16 pre-scale. LDS 52.6 KB
// -> 3 blocks/CU. Everything else byte-identical to R20.
// ---------------------------------------------------------------------------

typedef _Float16 half_t;
typedef __attribute__((ext_vector_type(8))) _Float16 half8;
typedef __attribute__((ext_vector_type(4))) _Float16 half4;
typedef __attribute__((ext_vector_type(4))) float    f32x4;

#define MFMA16x32(A_, B_, C_) __builtin_amdgcn_mfma_f32_16x16x32_f16((A_), (B_), (C_), 0, 0, 0)

__device__ __forceinline__ void gload_lds16(const void* g, void* l) {
  __builtin_amdgcn_global_load_lds(
      (const __attribute__((address_space(1))) void*)g,
      (__attribute__((address_space(3))) void*)l, 16, 0, 0);
}

// 16-lane-group reductions via DPP (validated R7+ / R19+).
__device__ __forceinline__ float dpp_max16(float x) {
  int t;
  t = __builtin_amdgcn_update_dpp(__float_as_int(x), __float_as_int(x), 0xB1, 0xF, 0xF, false);
  x = fmaxf(x, __int_as_float(t));
  t = __builtin_amdgcn_update_dpp(__float_as_int(x), __float_as_int(x), 0x4E, 0xF, 0xF, false);
  x = fmaxf(x, __int_as_float(t));
  t = __builtin_amdgcn_update_dpp(__float_as_int(x), __float_as_int(x), 0x124, 0xF, 0xF, false);
  x = fmaxf(x, __int_as_float(t));
  t = __builtin_amdgcn_update_dpp(__float_as_int(x), __float_as_int(x), 0x128, 0xF, 0xF, false);
  x = fmaxf(x, __int_as_float(t));
  return x;
}
__device__ __forceinline__ float dpp_sum16(float x) {
  int t;
  t = __builtin_amdgcn_update_dpp(__float_as_int(x), __float_as_int(x), 0xB1, 0xF, 0xF, false);
  x += __int_as_float(t);
  t = __builtin_amdgcn_update_dpp(__float_as_int(x), __float_as_int(x), 0x4E, 0xF, 0xF, false);
  x += __int_as_float(t);
  t = __builtin_amdgcn_update_dpp(__float_as_int(x), __float_as_int(x), 0x124, 0xF, 0xF, false);
  x += __int_as_float(t);
  t = __builtin_amdgcn_update_dpp(__float_as_int(x), __float_as_int(x), 0x128, 0xF, 0xF, false);
  x += __int_as_float(t);
  return x;
}

// ---- merged cast: x + Wq + Wk + Wv in one launch ----------------------------
__global__ void cast_all(const float* __restrict__ x, const float* __restrict__ Wq,
                         const float* __restrict__ Wk, const float* __restrict__ Wv,
                         half_t* __restrict__ xh, half_t* __restrict__ wqh,
                         half_t* __restrict__ wkh, half_t* __restrict__ wvh) {
  int idx = blockIdx.x * 256 + threadIdx.x;   // float4 index
  const float* s;
  half_t* d;
  int off;
  if (idx < 2097152) { s = x; d = xh; off = idx; }
  else {
    int w = idx - 2097152;
    int which = w >> 16;
    off = w & 65535;
    s = (which == 0) ? Wq : (which == 1) ? Wk : Wv;
    d = (which == 0) ? wqh : (which == 1) ? wkh : wvh;
  }
  f32x4 v = ((const f32x4*)s)[off];
  half4 h;
#pragma unroll
  for (int j = 0; j < 4; ++j) h[j] = (_Float16)v[j];
  *(half4*)&d[(size_t)off * 4] = h;
}

// ---- GEMM core (proven) -----------------------------------------------------
template <int NKT, int SA, int SB, int MR>
__device__ __forceinline__ void gemm_core(
    const char* Abytes, const char* Bbytes,
    half_t* At, half_t* Bt, int tid, f32x4 (&acc)[MR][4]) {
  const int lane = tid & 63;
  const int wv = tid >> 6;
  const int g = lane >> 4, li = lane & 15;
  const int wm = wv >> 1, wn = wv & 1;
  const int ASTRIDE = MR * 2048;

  auto STAGE = [&](int kc, int buf) {
#pragma unroll
    for (int i2 = 0; i2 < MR; ++i2) {
      int seg = i2 * 256 + tid;
      int row = seg >> 3, blk = seg & 7;
      int bsrc = blk ^ (row & 7);
      gload_lds16(Abytes + ((size_t)row * SA + kc + bsrc * 8) * 2,
                  (void*)&At[buf * ASTRIDE + seg * 8]);
    }
#pragma unroll
    for (int i2 = 0; i2 < 4; ++i2) {
      int seg = i2 * 256 + tid;
      int row = seg >> 3, blk = seg & 7;
      int bsrc = blk ^ (row & 7);
      gload_lds16(Bbytes + ((size_t)row * SB + kc + bsrc * 8) * 2,
                  (void*)&Bt[buf * 8192 + seg * 8]);
    }
  };

  STAGE(0, 0);
  __syncthreads();
  int cur = 0;
#pragma unroll 1
  for (int kt = 0; kt < NKT; ++kt) {
    if (kt + 1 < NKT) STAGE((kt + 1) * 64, cur ^ 1);
#pragma unroll
    for (int kk = 0; kk < 2; ++kk) {
      half8 af[MR], bf[4];
#pragma unroll
      for (int i = 0; i < MR; ++i) {
        int ar = wm * (MR * 16) + i * 16 + li;
        af[i] = *(const half8*)&At[cur * ASTRIDE + ar * 64 + (((4 * kk + g) ^ (ar & 7)) * 8)];
      }
#pragma unroll
      for (int j = 0; j < 4; ++j) {
        int br = wn * 64 + j * 16 + li;
        bf[j] = *(const half8*)&Bt[cur * 8192 + br * 64 + (((4 * kk + g) ^ (br & 7)) * 8)];
      }
#pragma unroll
      for (int i = 0; i < MR; ++i)
#pragma unroll
        for (int j = 0; j < 4; ++j) acc[i][j] = MFMA16x32(af[i], bf[j], acc[i][j]);
    }
    __syncthreads();
    cur ^= 1;
  }
}

// ---- projection GEMM (unchanged) --------------------------------------------
// MODE 2: out[t*512 + m] (q/k compact); MODE 1: out[m*16384 + t] (v transposed)
template <int MODE>
__global__ __launch_bounds__(256) void proj_gemm(
    const half_t* __restrict__ A, const half_t* __restrict__ Bm,
    const float* __restrict__ bias, half_t* __restrict__ out) {
  __shared__ half_t At[2 * 4 * 2048];
  __shared__ half_t Bt[2 * 8192];
  const int tid = threadIdx.x;
  const int lane = tid & 63, wv = tid >> 6;
  const int g = lane >> 4, li = lane & 15;
  const int wm = wv >> 1, wn = wv & 1;
  const int M0 = blockIdx.x * 128, N0 = blockIdx.y * 128;

  const f32x4 kZero = {0.f, 0.f, 0.f, 0.f};
  f32x4 acc[4][4];
#pragma unroll
  for (int i = 0; i < 4; ++i)
#pragma unroll
    for (int j = 0; j < 4; ++j) acc[i][j] = kZero;

  gemm_core<8, 512, 512, 4>((const char*)(A + (size_t)M0 * 512),
                            (const char*)(Bm + (size_t)N0 * 512), At, Bt, tid, acc);

  if (MODE == 2) {
#pragma unroll
    for (int i = 0; i < 4; ++i) {
      int trow = M0 + wm * 64 + i * 16 + 4 * g;
#pragma unroll
      for (int j = 0; j < 4; ++j) {
        int m = N0 + wn * 64 + j * 16 + li;
        float bs = bias[m];
#pragma unroll
        for (int r = 0; r < 4; ++r) {
          out[(size_t)(trow + r) * 512 + m] = (_Float16)(acc[i][j][r] + bs);
        }
      }
    }
  } else {
#pragma unroll
    for (int i = 0; i < 4; ++i) {
      int m0r = M0 + wm * 64 + i * 16 + 4 * g;
#pragma unroll
      for (int r = 0; r < 4; ++r) {
        int m = m0r + r;
        float bs = bias[m];
#pragma unroll
        for (int j = 0; j < 4; ++j) {
          int t = N0 + wn * 64 + j * 16 + li;
          out[(size_t)m * 16384 + t] = (_Float16)(acc[i][j][r] + bs);
        }
      }
    }
  }
}

// ---- S-GEMM + epilogue blockwise softmax (unchanged from R20) ---------------
__global__ __launch_bounds__(256) void s_pmax(
    const half_t* __restrict__ q, const half_t* __restrict__ k,
    half_t* __restrict__ Pp, float* __restrict__ m_t, float* __restrict__ l_t) {
  __shared__ half_t At[2 * 2 * 2048];
  __shared__ half_t Bt[2 * 8192];
  __shared__ float  mx2[2][64];
  __shared__ float  sm2[2][64];
  const int tid = threadIdx.x;
  const int lane = tid & 63, wv = tid >> 6;
  const int g = lane >> 4, li = lane & 15;
  const int wm = wv >> 1, wn = wv & 1;
  const int id = blockIdx.x;
  const int b = id & 7;
  const int idx = id >> 3;
  const int M0 = (idx & 31) * 64;
  const int N0 = (idx >> 5) * 128;
  const int tile = idx >> 5;

  const f32x4 kZero = {0.f, 0.f, 0.f, 0.f};
  f32x4 acc[2][4];
#pragma unroll
  for (int i = 0; i < 2; ++i)
#pragma unroll
    for (int j = 0; j < 4; ++j) acc[i][j] = kZero;

  gemm_core<8, 512, 512, 2>(
      (const char*)(q + (size_t)(b * 2048 + M0) * 512),
      (const char*)(k + (size_t)(b * 2048 + N0) * 512), At, Bt, tid, acc);

  float lmax[2][4];
#pragma unroll
  for (int i = 0; i < 2; ++i)
#pragma unroll
    for (int r = 0; r < 4; ++r) {
      float v = fmaxf(fmaxf(acc[i][0][r], acc[i][1][r]),
                      fmaxf(acc[i][2][r], acc[i][3][r]));
      lmax[i][r] = dpp_max16(v);
    }
  if (li == 0) {
#pragma unroll
    for (int i = 0; i < 2; ++i)
#pragma unroll
      for (int r = 0; r < 4; ++r)
        mx2[wn][wm * 32 + i * 16 + 4 * g + r] = lmax[i][r];
  }
  __syncthreads();

  const size_t grow0 = (size_t)(b * 2048 + M0 + wm * 32);
  float tsum[2][4];
#pragma unroll
  for (int i = 0; i < 2; ++i) {
#pragma unroll
    for (int r = 0; r < 4; ++r) {
      int lr = wm * 32 + i * 16 + 4 * g + r;
      float m = fmaxf(mx2[0][lr], mx2[1][lr]);
      float s = 0.f;
#pragma unroll
      for (int j = 0; j < 4; ++j) {
        float p = __expf(acc[i][j][r] - m);
        s += p;
        Pp[(grow0 + i * 16 + 4 * g + r) * 2048 + N0 + wn * 64 + j * 16 + li] =
            (_Float16)p;
      }
      tsum[i][r] = dpp_sum16(s);
      lmax[i][r] = m;
    }
  }
  if (li == 0) {
#pragma unroll
    for (int i = 0; i < 2; ++i)
#pragma unroll
      for (int r = 0; r < 4; ++r)
        sm2[wn][wm * 32 + i * 16 + 4 * g + r] = tsum[i][r];
  }
  __syncthreads();
  if (wn == 0 && li == 0) {
#pragma unroll
    for (int i = 0; i < 2; ++i)
#pragma unroll
      for (int r = 0; r < 4; ++r) {
        int lr = wm * 32 + i * 16 + 4 * g + r;
        m_t[(grow0 + i * 16 + 4 * g + r) * 16 + tile] = lmax[i][r];
        l_t[(grow0 + i * 16 + 4 * g + r) * 16 + tile] = sm2[0][lr] + sm2[1][lr];
      }
  }
}

// ---- merge tiles (unchanged) ------------------------------------------------
__global__ void sm_merge(const float* __restrict__ m_t, const float* __restrict__ l_t,
                         float* __restrict__ sc_g, float* __restrict__ l_fin) {
  int rr = blockIdx.x * 256 + threadIdx.x;
  float m[16];
  float mg = -3e38f;
#pragma unroll
  for (int t = 0; t < 16; ++t) { m[t] = m_t[rr * 16 + t]; mg = fmaxf(mg, m[t]); }
  float l = 0.f;
#pragma unroll
  for (int t = 0; t < 16; ++t) {
    float s = __expf(m[t] - mg);
    sc_g[rr * 16 + t] = s;
    l += l_t[rr * 16 + t] * s;
  }
  l_fin[rr] = l;
}

// ---- PV-GEMM v3 (fold-scaled): out = (sum_t sc_t * (P'_t . V_t)) / (l*sqrt512)
// grid 1024: b = id&7; idx = id>>3: M0 = (idx>>2)*64, N0 = (idx&3)*128.
// A (P', unscaled) and B both via global_load_lds — the proven core shape.
// Per 128-col k-tile (2 K-steps): MFMA into tmp, then acc += sc[row][t]*tmp.
__global__ __launch_bounds__(256) void pv_gemm(
    const half_t* __restrict__ Pp, const half_t* __restrict__ vt,
    const float* __restrict__ sc_g, const float* __restrict__ l_fin,
    float* __restrict__ outp) {
  __shared__ half_t At[2][4096];       // 2 x 8 KB (64 rows x 64 halves)
  __shared__ half_t Bt[2][8192];       // 2 x 16 KB (128 rows x 64)
  __shared__ float  sc[64][17];        // per-(row, 128-tile) scale, padded
  const int tid = threadIdx.x;
  const int lane = tid & 63, wv = tid >> 6;
  const int g = lane >> 4, li = lane & 15;
  const int wm = wv >> 1, wn = wv & 1;
  const int id = blockIdx.x;
  const int b = id & 7;
  const int idx = id >> 3;
  const int M0 = (idx >> 2) * 64;      // c within batch
  const int N0 = (idx & 3) * 128;      // n
  const int rgb = b * 2048 + M0;

  // scales -> LDS (1024 entries, 4/thread)
#pragma unroll
  for (int i2 = 0; i2 < 4; ++i2) {
    int e = i2 * 256 + tid;
    int row = e >> 4, t = e & 15;
    sc[row][t] = sc_g[(size_t)(rgb + row) * 16 + t];
  }

  const char* Ab = (const char*)(Pp + (size_t)rgb * 2048);
  const char* Bb = (const char*)(vt + (size_t)N0 * 16384 + (size_t)b * 2048);

  auto STAGE = [&](int kt, int buf) {
#pragma unroll
    for (int i2 = 0; i2 < 2; ++i2) {   // A: 64 rows x 8 blks = 512 segs
      int seg = i2 * 256 + tid;
      int row = seg >> 3, blk = seg & 7;
      int bsrc = blk ^ (row & 7);
      gload_lds16(Ab + ((size_t)row * 2048 + kt * 64 + bsrc * 8) * 2,
                  (void*)&At[buf][seg * 8]);
    }
#pragma unroll
    for (int i2 = 0; i2 < 4; ++i2) {   // B: 128 rows x 8 blks = 1024 segs
      int seg = i2 * 256 + tid;
      int row = seg >> 3, blk = seg & 7;
      int bsrc = blk ^ (row & 7);
      gload_lds16(Bb + ((size_t)row * 16384 + kt * 64 + bsrc * 8) * 2,
                  (void*)&Bt[buf][seg * 8]);
    }
  };

  STAGE(0, 0);
  __syncthreads();   // also covers sc visibility

  const f32x4 kZero = {0.f, 0.f, 0.f, 0.f};
  f32x4 acc[2][4];
#pragma unroll
  for (int i = 0; i < 2; ++i)
#pragma unroll
    for (int j = 0; j < 4; ++j) acc[i][j] = kZero;

  int cur = 0;
#pragma unroll 1
  for (int t16 = 0; t16 < 16; ++t16) {
    f32x4 tmp[2][4];
#pragma unroll
    for (int i = 0; i < 2; ++i)
#pragma unroll
      for (int j = 0; j < 4; ++j) tmp[i][j] = kZero;

#pragma unroll
    for (int hh = 0; hh < 2; ++hh) {
      int kt = t16 * 2 + hh;
      if (kt + 1 < 32) STAGE(kt + 1, cur ^ 1);
#pragma unroll
      for (int kk = 0; kk < 2; ++kk) {
        half8 af[2], bf[4];
#pragma unroll
        for (int i = 0; i < 2; ++i) {
          int ar = wm * 32 + i * 16 + li;
          af[i] = *(const half8*)&At[cur][ar * 64 + (((4 * kk + g) ^ (ar & 7)) * 8)];
        }
#pragma unroll
        for (int j = 0; j < 4; ++j) {
          int br = wn * 64 + j * 16 + li;
          bf[j] = *(const half8*)&Bt[cur][br * 64 + (((4 * kk + g) ^ (br & 7)) * 8)];
        }
#pragma unroll
        for (int i = 0; i < 2; ++i)
#pragma unroll
          for (int j = 0; j < 4; ++j) tmp[i][j] = MFMA16x32(af[i], bf[j], tmp[i][j]);
      }
      __syncthreads();
      cur ^= 1;
    }

    // fold: acc += sc[row][t16] * tmp  (fp32)
#pragma unroll
    for (int i = 0; i < 2; ++i) {
#pragma unroll
      for (int r = 0; r < 4; ++r) {
        float s = sc[wm * 32 + i * 16 + 4 * g + r][t16];
#pragma unroll
        for (int j = 0; j < 4; ++j) acc[i][j][r] += s * tmp[i][j][r];
      }
    }
  }

  // epilogue: 1/(l*sqrt(512)), transposed scatter out[b][n][c]
#pragma unroll
  for (int i = 0; i < 2; ++i) {
    int c0r = M0 + wm * 32 + i * 16 + 4 * g;
    float inv[4];
#pragma unroll
    for (int r = 0; r < 4; ++r)
      inv[r] = 1.0f / (l_fin[b * 2048 + c0r + r] * 22.62741699796952f);
#pragma unroll
    for (int j = 0; j < 4; ++j) {
      int n = N0 + wn * 64 + j * 16 + li;
      float* ob = outp + (size_t)b * 1048576 + (size_t)n * 2048 + c0r;
#pragma unroll
      for (int r = 0; r < 4; ++r) {
        ob[r] = acc[i][j][r] * inv[r];
      }
    }
  }
}

// ---------------------------------------------------------------------------
extern "C" void kernel_launch(void* const* d_in, const int* in_sizes, int n_in,
                              void* d_out, int out_size, void* d_ws, size_t ws_size,
                              hipStream_t stream) {
  const float* x  = (const float*)d_in[0];
  const float* Wq = (const float*)d_in[1];
  const float* bq = (const float*)d_in[2];
  const float* Wk = (const float*)d_in[3];
  const float* bk = (const float*)d_in[4];
  const float* Wv = (const float*)d_in[5];
  const float* bv = (const float*)d_in[6];

  // workspace layout:
  half_t* qsb  = (half_t*)d_ws;                     // [16384][512]   16 MB
  half_t* ksb  = qsb + (size_t)16384 * 512;         // [16384][512]   16 MB
  half_t* vtb  = ksb + (size_t)16384 * 512;         // [512][16384]   16 MB
  half_t* Pp   = vtb + (size_t)512 * 16384;         // [16384][2048]  67 MB (attn)
  half_t* xh   = Pp;                                // [16384][512]   (proj phase)
  half_t* wqh  = xh  + (size_t)16384 * 512;
  half_t* wkh  = wqh + (size_t)512 * 512;
  half_t* wvh  = wkh + (size_t)512 * 512;
  float*  m_t  = (float*)(Pp + (size_t)16384 * 2048);   // [16384][16]  1 MB
  float*  l_t  = m_t + (size_t)16384 * 16;              // [16384][16]  1 MB
  float*  sc_g = l_t + (size_t)16384 * 16;              // [16384][16]  1 MB
  float*  l_fin = sc_g + (size_t)16384 * 16;            // [16384]

  cast_all<<<dim3(8960), 256, 0, stream>>>(x, Wq, Wk, Wv, xh, wqh, wkh, wvh);

  proj_gemm<2><<<dim3(128, 4), 256, 0, stream>>>(xh, wqh, bq, qsb);
  proj_gemm<2><<<dim3(128, 4), 256, 0, stream>>>(xh, wkh, bk, ksb);
  proj_gemm<1><<<dim3(4, 128), 256, 0, stream>>>(wvh, xh, bv, vtb);

  s_pmax<<<dim3(4096), 256, 0, stream>>>(qsb, ksb, Pp, m_t, l_t);
  sm_merge<<<dim3(64), 256, 0, stream>>>(m_t, l_t, sc_g, l_fin);
  pv_gemm<<<dim3(1024), 256, 0, stream>>>(Pp, vtb, sc_g, l_fin, (float*)d_out);
}